// Round 7
// baseline (1058.139 us; speedup 1.0000x reference)
//
#include <hip/hip_runtime.h>
#include <hip/hip_bf16.h>

// AudioLSTM fused persistent kernel, v15: v14 + 2-STEP PIPELINED STAGING.
// B=512, T=1000, IN=26, H1=64, H2=32, FC 32->16->10.
// 32 blocks x 512 threads (8 waves), one 16-elem group per block.
// v14 post-mortem (822us == v13's 826): the per-step staging wave does
// load->convert->write within one step; x is read once (no L2 reuse) so the
// wave eats ~600-900cy cold-HBM latency EVERY step and the barrier makes it
// the block's pace-setter -- cancelling v14's xg-in-reg/wave-count wins.
// v15: split staging across steps (T14): at step s, WRITE the slice loaded
// at s-2 (latency hidden under 2 full steps) and ISSUE loads for s+2.
// Static two-bank regs (fbA/fbB by s&1 branch -- no runtime indexing).
// All compute identical to v14: f16 MFMA frags, prescaled gates, pair-rcp.

typedef __hip_bfloat16 bf16;
typedef _Float16 f16;
typedef _Float16 f16x8 __attribute__((ext_vector_type(8)));
typedef _Float16 f16x4 __attribute__((ext_vector_type(4)));
typedef float    f32x4 __attribute__((ext_vector_type(4)));

#define T_STEPS 1000
#define IN_DIM  26
#define EPB     16      // batch elems per block/group
#define CH      16      // staged x chunk length (timesteps)
#define NCHUNK  62      // last chunk index = (T_STEPS-1)/CH
#define H1P     72      // padded h1 row (f16): 144B
#define H2P     40      // padded h2 row (f16): 80B
#define XP      40      // padded Xst row (f16): 80B

#define NL2E  -1.4426950408889634f   // -log2(e): i,f,o gate prescale
#define N2L2E -2.8853900817779268f   // -2log2(e): g gate prescale

__device__ __forceinline__ float bits2f(unsigned short h) {
    return __uint_as_float(((unsigned int)h) << 16);
}
__device__ __forceinline__ float ldv(const void* p, long i, bool isb) {
    return isb ? bits2f(((const unsigned short*)p)[i]) : ((const float*)p)[i];
}
__device__ __forceinline__ float rcp_(float x) { return __builtin_amdgcn_rcpf(x); }
__device__ __forceinline__ float ex2_(float x) { return __builtin_amdgcn_exp2f(x); }

// Prescaled pre-activations (yi=-log2e*pi, yg=-2log2e*pg, ...).
// Updates c, returns h = sigm(o)*tanh(c). 5 exp2 + 3 rcp + ~13 VALU.
__device__ __forceinline__ float lstm_act(float yi, float yf, float yg,
                                          float yo, float& c) {
    const float A  = ex2_(yi), F = ex2_(yf), B = ex2_(yg), O = ex2_(yo);
    const float a1 = 1.f + A, f1 = 1.f + F, b1 = 1.f + B, o1 = 1.f + O;
    const float ig = (2.f - b1) * rcp_(a1 * b1);     // sigm(i)*tanh(g)
    c = fmaf(rcp_(f1), c, ig);                       // f*c + i*g
    const float C2  = ex2_(N2L2E * c);               // e^(-2c)
    const float c1p = 1.f + C2;
    return (2.f - c1p) * rcp_(o1 * c1p);             // sigm(o)*tanh(c)
}

#define MFMA(a, b, c) __builtin_amdgcn_mfma_f32_16x16x32_f16((a), (b), (c), 0, 0, 0)

__global__
__attribute__((amdgpu_flat_work_group_size(512, 512), amdgpu_waves_per_eu(2, 2)))
void lstm_fused(const void* __restrict__ x,
                const void* __restrict__ w_ih1, const void* __restrict__ w_hh1,
                const void* __restrict__ b_ih1, const void* __restrict__ b_hh1,
                const void* __restrict__ w_ih2, const void* __restrict__ w_hh2,
                const void* __restrict__ b_ih2, const void* __restrict__ b_hh2,
                const void* __restrict__ w_fc1, const void* __restrict__ b_fc1,
                const void* __restrict__ w_fc2, const void* __restrict__ b_fc2,
                void* __restrict__ out)
{
    const int tid  = threadIdx.x;      // 0..511
    const int lane = tid & 63;
    const int wv   = tid >> 6;         // 0..7
    const int ecol = lane & 15;        // MFMA N-col = elem within group
    const int g4   = lane >> 4;        // lane group 0..3
    const int r15  = lane & 15;
    const int e0   = blockIdx.x * EPB;

    __shared__ __align__(16) f16   Xst[2][CH][EPB][XP];  // 40960 B
    __shared__ __align__(16) f16   H1T[2][EPB][H1P];     // 4608 B
    __shared__ __align__(16) f16   H2T[2][EPB][H2P];     // 2560 B
    __shared__ __align__(16) float f1s[EPB][16];         // 1024 B

    // ---- runtime dtype detection (uniform): w_ih1 ~ U(-1/8,1/8) ----
    bool isb = true;
    {
        const unsigned short* wu = (const unsigned short*)w_ih1;
        for (int k = 0; k < 64; ++k) {
            float v = fabsf(bits2f(wu[k]));
            if (!(v <= 0.1251f)) isb = false;
        }
    }

    // ---- zero LDS (x k-pad, h pads, h1[-1]=h2[-1]=0) ----
    {
        float4 z; z.x = z.y = z.z = z.w = 0.f;
        float4* p = (float4*)&Xst[0][0][0][0];
        for (int k = tid; k < (int)(sizeof(Xst) / 16); k += 512) p[k] = z;
        float4* q = (float4*)&H1T[0][0][0];
        for (int k = tid; k < (int)(sizeof(H1T) / 16); k += 512) q[k] = z;
        float4* r = (float4*)&H2T[0][0][0];
        for (int k = tid; k < (int)(sizeof(H2T) / 16); k += 512) r[k] = z;
    }

    // ---- role weight fragments (A-frag: row = lane&15, k = 8*g4+j) ----
    f16x8 W8[8]; f16x8 W4[4]; f32x4 C4[4];
    if (wv < 4) {
#pragma unroll
        for (int gi = 0; gi < 4; ++gi) {
            const float sc = (gi == 2) ? N2L2E : NL2E;
            const int R = gi * 64 + 16 * wv + r15;
#pragma unroll
            for (int k0 = 0; k0 < 2; ++k0)
#pragma unroll
                for (int jj = 0; jj < 8; ++jj)
                    W8[gi * 2 + k0][jj] =
                        (f16)(sc * ldv(w_hh1, R * 64 + k0 * 32 + g4 * 8 + jj, isb));
#pragma unroll
            for (int jj = 0; jj < 8; ++jj) {
                const int k = g4 * 8 + jj;
                W4[gi][jj] =
                    (f16)(k < IN_DIM ? sc * ldv(w_ih1, R * IN_DIM + k, isb) : 0.f);
            }
#pragma unroll
            for (int jj = 0; jj < 4; ++jj) {
                const int Rc = gi * 64 + 16 * wv + g4 * 4 + jj;
                C4[gi][jj] = sc * (ldv(b_ih1, Rc, isb) + ldv(b_hh1, Rc, isb));
            }
        }
    } else if (wv < 6) {
        const int hf = wv - 4;
#pragma unroll
        for (int gi = 0; gi < 4; ++gi) {
            const float sc = (gi == 2) ? N2L2E : NL2E;
            const int R = gi * 32 + 16 * hf + r15;
#pragma unroll
            for (int k0 = 0; k0 < 2; ++k0)
#pragma unroll
                for (int jj = 0; jj < 8; ++jj)
                    W8[gi * 2 + k0][jj] =
                        (f16)(sc * ldv(w_ih2, R * 64 + k0 * 32 + g4 * 8 + jj, isb));
#pragma unroll
            for (int jj = 0; jj < 8; ++jj)
                W4[gi][jj] = (f16)(sc * ldv(w_hh2, R * 32 + g4 * 8 + jj, isb));
#pragma unroll
            for (int jj = 0; jj < 4; ++jj) {
                const int Rc = gi * 32 + 16 * hf + g4 * 4 + jj;
                C4[gi][jj] = sc * (ldv(b_ih2, Rc, isb) + ldv(b_hh2, Rc, isb));
            }
        }
    }

    __syncthreads();   // LDS zeroed before staging overwrites i<26

    // sync stage of one (e,i) row of chunk c (prologue only)
    auto stageRow = [&](int p, int c) {
        const int t0 = c * CH;
        const int nt = (T_STEPS - t0 < CH) ? (T_STEPS - t0) : CH;
        const int e = p / IN_DIM, i = p - e * IN_DIM;
        const long gb = ((long)(e0 + e) * IN_DIM + i) * T_STEPS + t0;
        float4 fb[4];
        if (isb) {
            const float4* q = (const float4*)((const unsigned short*)x + gb);
            fb[0] = q[0]; if (nt > 8) fb[1] = q[1];
        } else {
            const float4* q = (const float4*)((const float*)x + gb);
            fb[0] = q[0]; fb[1] = q[1];
            if (nt > 8) { fb[2] = q[2]; fb[3] = q[3]; }
        }
#pragma unroll
        for (int t = 0; t < CH; ++t) if (t < nt) {
            float v;
            if (isb) {
                unsigned int u =
                    __builtin_bit_cast(unsigned int, fb[t >> 3][(t >> 1) & 3]);
                v = bits2f((t & 1) ? (unsigned short)(u >> 16)
                                   : (unsigned short)(u & 0xffffu));
            } else {
                v = fb[t >> 2][t & 3];
            }
            Xst[c & 1][t][e][i] = (f16)v;
        }
    };

    // pipelined staging: slice of write-step sw covers chunk c=((sw+1)>>4)+1,
    // slice (sw+1)&15, rows slice*26 + base (base = (wv-6)*13 + lane, lane<13)
    auto stLoad = [&](int sw, int base, float4 (&fb)[4]) {
        const int s1 = sw + 1, c = (s1 >> 4) + 1;
        if (c > NCHUNK) return;
        const int p = (s1 & 15) * 26 + base;
        const int e = p / IN_DIM, i = p - e * IN_DIM;
        const int t0 = c * CH;
        const int nt = (T_STEPS - t0 < CH) ? (T_STEPS - t0) : CH;
        const long gb = ((long)(e0 + e) * IN_DIM + i) * T_STEPS + t0;
        if (isb) {
            const float4* q = (const float4*)((const unsigned short*)x + gb);
            fb[0] = q[0]; if (nt > 8) fb[1] = q[1];
        } else {
            const float4* q = (const float4*)((const float*)x + gb);
            fb[0] = q[0]; fb[1] = q[1];
            if (nt > 8) { fb[2] = q[2]; fb[3] = q[3]; }
        }
    };
    auto stWrite = [&](int sw, int base, const float4 (&fb)[4]) {
        const int s1 = sw + 1, c = (s1 >> 4) + 1;
        if (c > NCHUNK) return;
        const int p = (s1 & 15) * 26 + base;
        const int e = p / IN_DIM, i = p - e * IN_DIM;
        const int t0 = c * CH;
        const int nt = (T_STEPS - t0 < CH) ? (T_STEPS - t0) : CH;
#pragma unroll
        for (int t = 0; t < CH; ++t) if (t < nt) {
            float v;
            if (isb) {
                unsigned int u =
                    __builtin_bit_cast(unsigned int, fb[t >> 3][(t >> 1) & 3]);
                v = bits2f((t & 1) ? (unsigned short)(u >> 16)
                                   : (unsigned short)(u & 0xffffu));
            } else {
                v = fb[t >> 2][t & 3];
            }
            Xst[c & 1][t][e][i] = (f16)v;
        }
    };

    // prologue: chunk 0 fully (416 rows) + chunk 1 slice 0 (rows 0..25)
    if (tid < EPB * IN_DIM) stageRow(tid, 0);
    if (tid >= 448 && tid < 448 + 26) stageRow(tid - 448, 1);

    // staging pipeline prologue: preload banks for write-steps 0 (A) and 1 (B)
    float4 fbA[4], fbB[4];
    const int sbase = (wv - 6) * 13 + lane;
    if (wv >= 6 && lane < 13) {
        stLoad(0, sbase, fbA);
        stLoad(1, sbase, fbB);
    }
    __syncthreads();

    // xg[0] into registers (LSTM1 waves; C-layout, prescaled bias folded in)
    f32x4 xgc[4];
    if (wv < 4) {
        const f16x8 xf = *(const f16x8*)&Xst[0][0][ecol][g4 * 8];
#pragma unroll
        for (int gi = 0; gi < 4; ++gi) xgc[gi] = MFMA(W4[gi], xf, C4[gi]);
    }

    if (wv < 6) __builtin_amdgcn_s_setprio(1);   // compute waves get priority

    float cst[4] = {0.f, 0.f, 0.f, 0.f};   // c1 (wv0-3) or c2 (wv4-5)

    for (int s = 0; s <= T_STEPS; ++s) {
        const int pc = s & 1, pp = pc ^ 1;

        if (wv < 4) {
            // ==== LSTM1 unit-group wv (+ own xg pipeline) ====
            if (s < T_STEPS) {
                const f16x8 h1f0 = *(const f16x8*)&H1T[pp][ecol][g4 * 8];
                const f16x8 h1f1 = *(const f16x8*)&H1T[pp][ecol][32 + g4 * 8];
                const bool nx = (s + 1 < T_STEPS);
                f16x8 xf = {};
                if (nx) {
                    const int sn = s + 1;
                    xf = *(const f16x8*)&Xst[(sn >> 4) & 1][sn & 15][ecol][g4 * 8];
                }
                f32x4 gt[4];
#pragma unroll
                for (int gi = 0; gi < 4; ++gi) {
                    f32x4 t0 = MFMA(W8[gi * 2 + 0], h1f0, xgc[gi]);  // C = xg
                    gt[gi]   = MFMA(W8[gi * 2 + 1], h1f1, t0);
                }
                f32x4 xgn[4];
                if (nx) {
#pragma unroll
                    for (int gi = 0; gi < 4; ++gi)
                        xgn[gi] = MFMA(W4[gi], xf, C4[gi]);          // xg[s+1]
                }
                f16x4 hh;
#pragma unroll
                for (int jj = 0; jj < 4; ++jj)        // unit 16*wv + 4*g4 + jj
                    hh[jj] = (f16)lstm_act(gt[0][jj], gt[1][jj],
                                           gt[2][jj], gt[3][jj], cst[jj]);
                *(f16x4*)&H1T[pc][ecol][16 * wv + g4 * 4] = hh;
                if (nx) {
#pragma unroll
                    for (int gi = 0; gi < 4; ++gi) xgc[gi] = xgn[gi];
                }
            }
        } else if (wv < 6) {
            // ==== LSTM2 step s-1 (half wv-4): h1[s-1], h2[s-2] ====
            if (s >= 1) {
                const int hf = wv - 4;
                const f16x8 h1f0 = *(const f16x8*)&H1T[pp][ecol][g4 * 8];
                const f16x8 h1f1 = *(const f16x8*)&H1T[pp][ecol][32 + g4 * 8];
                const f16x8 h2f  = *(const f16x8*)&H2T[pc][ecol][g4 * 8];
                f32x4 gt[4];
#pragma unroll
                for (int gi = 0; gi < 4; ++gi) {
                    f32x4 t0 = MFMA(W8[gi * 2 + 0], h1f0, C4[gi]);
                    t0       = MFMA(W8[gi * 2 + 1], h1f1, t0);
                    gt[gi]   = MFMA(W4[gi], h2f, t0);
                }
                f16x4 hh;
#pragma unroll
                for (int jj = 0; jj < 4; ++jj)        // unit 16*hf + 4*g4 + jj
                    hh[jj] = (f16)lstm_act(gt[0][jj], gt[1][jj],
                                           gt[2][jj], gt[3][jj], cst[jj]);
                *(f16x4*)&H2T[pp][ecol][16 * hf + g4 * 4] = hh;   // h2[s-1]
            }
        } else {
            // ==== staging (wv6-7): WRITE slice loaded 2 steps ago; ISSUE s+2
            if (lane < 13) {
                if ((s & 1) == 0) {
                    stWrite(s, sbase, fbA);
                    stLoad(s + 2, sbase, fbA);
                } else {
                    stWrite(s, sbase, fbB);
                    stLoad(s + 2, sbase, fbB);
                }
            }
        }

        __syncthreads();
    }

    // ---- FC head: h2[T-1] in H2T[1] (written at s=1000, pp=1) ----
    if (tid < EPB * 16) {
        const int e = tid >> 4, o = tid & 15;
        float ss = ldv(b_fc1, o, isb);
#pragma unroll 8
        for (int k = 0; k < 32; ++k)
            ss = fmaf(ldv(w_fc1, o * 32 + k, isb), (float)H2T[1][e][k], ss);
        f1s[e][o] = fmaxf(ss, 0.f);
    }
    __syncthreads();
    if (tid < EPB * 10) {
        const int e = tid / 10, o = tid - e * 10;
        float ss = ldv(b_fc2, o, isb);
#pragma unroll
        for (int k = 0; k < 16; ++k)
            ss = fmaf(ldv(w_fc2, o * 16 + k, isb), f1s[e][k], ss);
        const long oi = (long)(e0 + e) * 10 + o;
        if (isb) ((bf16*)out)[oi] = __float2bfloat16(ss);
        else     ((float*)out)[oi] = ss;
    }
}

extern "C" void kernel_launch(void* const* d_in, const int* in_sizes, int n_in,
                              void* d_out, int out_size, void* d_ws, size_t ws_size,
                              hipStream_t stream) {
    lstm_fused<<<dim3(512 / EPB), dim3(512), 0, stream>>>(
        d_in[0], d_in[1], d_in[2], d_in[3], d_in[4],
        d_in[5], d_in[6], d_in[7], d_in[8],
        d_in[9], d_in[10], d_in[11], d_in[12], d_out);
}